// Round 8
// baseline (2031.319 us; speedup 1.0000x reference)
//
#include <hip/hip_runtime.h>

#define NN 50000
#define NE 1600000
#define DIM 32
#define HS 0.1f
#define NBPS 782       // cdiv(NN, 64) blocks per sign

static inline int cdiv(int a, int b) { return (a + b - 1) / b; }

typedef float vf4 __attribute__((ext_vector_type(4)));
typedef unsigned vu4 __attribute__((ext_vector_type(4)));

__device__ __forceinline__ float4 nt_load_f4(const float* p) {
    vf4 v = __builtin_nontemporal_load((const vf4*)p);
    return make_float4(v.x, v.y, v.z, v.w);
}
__device__ __forceinline__ void nt_store_f4(float* p, float4 v) {
    vf4 t = {v.x, v.y, v.z, v.w};
    __builtin_nontemporal_store(t, (vf4*)p);
}
__device__ __forceinline__ uint4 nt_load_u4(const uint4* p) {
    vu4 v = __builtin_nontemporal_load((const vu4*)p);
    return make_uint4(v.x, v.y, v.z, v.w);
}
__device__ __forceinline__ void nt_store_u4(uint4* p, uint4 v) {
    vu4 t = {v.x, v.y, v.z, v.w};
    __builtin_nontemporal_store(t, (vu4*)p);
}

// bf16x4 (uint2) -> float4
__device__ __forceinline__ float4 bf4_to_f4(uint2 u) {
    float4 v;
    v.x = __uint_as_float(u.x << 16);
    v.y = __uint_as_float(u.x & 0xffff0000u);
    v.z = __uint_as_float(u.y << 16);
    v.w = __uint_as_float(u.y & 0xffff0000u);
    return v;
}
__device__ __forceinline__ unsigned pack_bf2(float a, float b) {
    unsigned ua = __float_as_uint(a);
    ua = (ua + 0x7fffu + ((ua >> 16) & 1u)) >> 16;
    unsigned ub = __float_as_uint(b);
    ub = (ub + 0x7fffu + ((ub >> 16) & 1u)) & 0xffff0000u;
    return ua | ub;
}

// ---------------- setup kernels ----------------

__global__ void k_zero_ints(int* __restrict__ p, int n) {
    int i = blockIdx.x * blockDim.x + threadIdx.x;
    if (i < n) p[i] = 0;
}

__global__ void k_hist(const int* __restrict__ dst, int* __restrict__ cnt) {
    int i = blockIdx.x * blockDim.x + threadIdx.x;
    if (i < NE) atomicAdd(&cnt[dst[i]], 1);
}

// degree histogram (128 bins, clamp)
__global__ void k_deghist(const int* __restrict__ cnt, int* __restrict__ H) {
    int n = blockIdx.x * blockDim.x + threadIdx.x;
    if (n < NN) atomicAdd(&H[min(cnt[n], 127)], 1);
}

// descending-degree bases: base[d] = #nodes with degree > d
__global__ void k_degbase(const int* __restrict__ H, int* __restrict__ base) {
    if (threadIdx.x == 0 && blockIdx.x == 0) {
        int run = 0;
        for (int d = 127; d >= 0; --d) { base[d] = run; run += H[d]; }
    }
}

// assign new ids (degree-descending), emit permutation + per-newid degree/dis
__global__ void k_newid(const int* __restrict__ cnt, const int* __restrict__ base,
                        int* __restrict__ Hc, int* __restrict__ newid,
                        int* __restrict__ oldid, int* __restrict__ degn,
                        float* __restrict__ disn, float* __restrict__ diso) {
    int n = blockIdx.x * blockDim.x + threadIdx.x;
    if (n < NN) {
        int d = cnt[n];
        int db = min(d, 127);
        int nid = base[db] + atomicAdd(&Hc[db], 1);
        newid[n] = nid;
        oldid[nid] = n;
        degn[nid] = d;
        float r = rsqrtf((float)d + 1.0f);  // +1 self-loop
        disn[nid] = r;
        diso[n] = r;
    }
}

// prefix over PADDED degree (rounded up to 8), new-id space -> row_ptr
__global__ __launch_bounds__(1024) void k_scanA(const int* __restrict__ degn,
                                                int* __restrict__ row_ptr,
                                                int* __restrict__ partials) {
    __shared__ int s[1024];
    int t = threadIdx.x;
    int g = blockIdx.x * 1024 + t;
    int v = (g < NN) ? ((degn[g] + 7) & ~7) : 0;
    s[t] = v;
    __syncthreads();
    for (int off = 1; off < 1024; off <<= 1) {
        int add = (t >= off) ? s[t - off] : 0;
        __syncthreads();
        s[t] += add;
        __syncthreads();
    }
    if (g < NN) row_ptr[g + 1] = s[t];
    if (t == 1023) partials[blockIdx.x] = s[t];
}

__global__ void k_scanB(int* __restrict__ partials, int nb) {
    if (threadIdx.x == 0 && blockIdx.x == 0) {
        int run = 0;
        for (int i = 0; i < nb; i++) { int v = partials[i]; partials[i] = run; run += v; }
    }
}

__global__ void k_scanC(int* __restrict__ row_ptr, const int* __restrict__ partials) {
    int g = blockIdx.x * blockDim.x + threadIdx.x;
    if (g < NN) row_ptr[g + 1] += partials[g >> 10];
    if (g == 0) row_ptr[0] = 0;
}

// scatter edges; rec = (newid[src] << 15) | fix15(dis[s]*dis[d]); CSR in new-id space
__global__ void k_fill(const int* __restrict__ src, const int* __restrict__ dst,
                       const int* __restrict__ row_ptr, const float* __restrict__ diso,
                       const int* __restrict__ newid,
                       int* __restrict__ fill, unsigned* __restrict__ cw) {
    int i = blockIdx.x * blockDim.x + threadIdx.x;
    if (i < NE) {
        int s = src[i], d = dst[i];
        int nd = newid[d];
        int slot = row_ptr[nd] + atomicAdd(&fill[nd], 1);
        float w = diso[s] * diso[d];   // in (0, 1]
        cw[slot] = ((unsigned)newid[s] << 15) | (unsigned)(w * 32767.f + 0.5f);
    }
}

// zero the pad slots (rec=0 -> src 0, weight 0)
__global__ void k_pad(const int* __restrict__ row_ptr, const int* __restrict__ degn,
                      unsigned* __restrict__ cw) {
    int n = blockIdx.x * blockDim.x + threadIdx.x;
    if (n < NN) {
        int e = row_ptr[n] + degn[n], e1 = row_ptr[n + 1];
        for (; e < e1; ++e) cw[e] = 0u;
    }
}

// ---------------- initial matmul (x @ W -> xw bf16 permuted, x -> x_cur permuted) ----

__global__ __launch_bounds__(256) void k_matmul(const float* __restrict__ src,
                                                const float* __restrict__ W,
                                                const int* __restrict__ newid,
                                                uint2* __restrict__ xw,
                                                float* __restrict__ copy_out) {
    __shared__ float sW[DIM * DIM];
    __shared__ float sX[32 * 33];
    int t = threadIdx.x;
#pragma unroll
    for (int k = 0; k < 4; k++) { int i = k * 256 + t; sW[i] = W[i]; }
    size_t base = (size_t)blockIdx.x * 32 * DIM;
#pragma unroll
    for (int k = 0; k < 4; k++) {
        int i = k * 256 + t;
        size_t g = base + i;
        float v = 0.f;
        if (g < (size_t)NN * DIM) {
            v = src[g];
            int ro = (int)(g >> 5), col = (int)(g & 31);
            copy_out[(size_t)newid[ro] * DIM + col] = v;
        }
        sX[(i >> 5) * 33 + (i & 31)] = v;
    }
    __syncthreads();
    int r = t >> 3, oct = t & 7;
    int row = blockIdx.x * 32 + r;
    if (row >= NN) return;
    float a0 = 0.f, a1 = 0.f, a2 = 0.f, a3 = 0.f;
    const float* xr = &sX[r * 33];
#pragma unroll
    for (int i = 0; i < DIM; i++) {
        float xv = xr[i];
        const float* wr = &sW[i * DIM + oct * 4];
        a0 = fmaf(xv, wr[0], a0);
        a1 = fmaf(xv, wr[1], a1);
        a2 = fmaf(xv, wr[2], a2);
        a3 = fmaf(xv, wr[3], a3);
    }
    xw[(size_t)newid[row] * 8 + oct] = make_uint2(pack_bf2(a0, a1), pack_bf2(a2, a3));
}

// ---------------- fused stage kernel ----------------
// All node-indexed arrays live in degree-sorted (new-id) space: within a wave
// the 16 lane-groups have near-equal degree -> minimal divergence. Streams
// (x_cur, acc, stores) are non-temporal; cw and gathers use normal caching.
// acc is bf16 (uint4 per lane-group).

struct SignP {
    const int* row_ptr; const unsigned* cw; const float* dis;
    const uint4* xw_in; uint4* xw_out;
    uint4* acc; float* x_cur;
    const float* W; const float* b; const float* wt;
    const int* oldid;
    float* zout;
};
struct StageArgs { SignP s[2]; float t, acc_coef, stage_coef; int mode; };

#define EDGE_FMA(r, u)                                              \
    {                                                               \
        float wE = (float)((r) & 32767u) * (1.f / 32767.f);         \
        float4 vA = bf4_to_f4(make_uint2((u).x, (u).y));            \
        float4 vB = bf4_to_f4(make_uint2((u).z, (u).w));            \
        sum0.x = fmaf(wE, vA.x, sum0.x);                            \
        sum0.y = fmaf(wE, vA.y, sum0.y);                            \
        sum0.z = fmaf(wE, vA.z, sum0.z);                            \
        sum0.w = fmaf(wE, vA.w, sum0.w);                            \
        sum1.x = fmaf(wE, vB.x, sum1.x);                            \
        sum1.y = fmaf(wE, vB.y, sum1.y);                            \
        sum1.z = fmaf(wE, vB.z, sum1.z);                            \
        sum1.w = fmaf(wE, vB.w, sum1.w);                            \
    }

__global__ __launch_bounds__(256) void k_stage(StageArgs A) {
    int sg = blockIdx.x & 1;       // with 8-XCD round-robin: sign per XCD parity
    int blk = blockIdx.x >> 1;
    SignP P = A.s[sg];

    __shared__ float sW[DIM * DIM];   // 4 KB
    __shared__ float sR[64 * 36];     // 9 KB; stride 36 floats
    int tid = threadIdx.x;
    if (A.mode != 5) {
#pragma unroll
        for (int k = 0; k < 4; k++) { int i = k * 256 + tid; sW[i] = P.W[i]; }
    }

    int c = tid & 3;              // column octet: cols c*8 .. c*8+7
    int nl = tid >> 2;            // local node 0..63
    int n = blk * 64 + nl;
    bool active = n < NN;
    float4 r40 = make_float4(0.f, 0.f, 0.f, 0.f);
    float4 r41 = make_float4(0.f, 0.f, 0.f, 0.f);

    if (active) {
        int e = P.row_ptr[n], e1 = P.row_ptr[n + 1];   // (e1-e) % 8 == 0
        const uint4* xwq = P.xw_in + c;   // row stride = 4 uint4 (64 B)
        float4 sum0 = make_float4(0.f, 0.f, 0.f, 0.f);
        float4 sum1 = make_float4(0.f, 0.f, 0.f, 0.f);
        unsigned r0, r1, r2, r3, r4, r5, r6, r7;
        if (e < e1) {
            r0 = P.cw[e];     r1 = P.cw[e + 1]; r2 = P.cw[e + 2]; r3 = P.cw[e + 3];
            r4 = P.cw[e + 4]; r5 = P.cw[e + 5]; r6 = P.cw[e + 6]; r7 = P.cw[e + 7];
        }
        while (e < e1) {
            uint4 u0 = xwq[(size_t)(r0 >> 15) * 4];
            uint4 u1 = xwq[(size_t)(r1 >> 15) * 4];
            uint4 u2 = xwq[(size_t)(r2 >> 15) * 4];
            uint4 u3 = xwq[(size_t)(r3 >> 15) * 4];
            uint4 u4 = xwq[(size_t)(r4 >> 15) * 4];
            uint4 u5 = xwq[(size_t)(r5 >> 15) * 4];
            uint4 u6 = xwq[(size_t)(r6 >> 15) * 4];
            uint4 u7 = xwq[(size_t)(r7 >> 15) * 4];
            int en = e + 8;
            unsigned t0, t1, t2, t3, t4, t5, t6, t7;
            if (en < e1) {
                t0 = P.cw[en];     t1 = P.cw[en + 1]; t2 = P.cw[en + 2]; t3 = P.cw[en + 3];
                t4 = P.cw[en + 4]; t5 = P.cw[en + 5]; t6 = P.cw[en + 6]; t7 = P.cw[en + 7];
            }
            EDGE_FMA(r0, u0) EDGE_FMA(r1, u1) EDGE_FMA(r2, u2) EDGE_FMA(r3, u3)
            EDGE_FMA(r4, u4) EDGE_FMA(r5, u5) EDGE_FMA(r6, u6) EDGE_FMA(r7, u7)
            if (en < e1) {
                r0 = t0; r1 = t1; r2 = t2; r3 = t3;
                r4 = t4; r5 = t5; r6 = t6; r7 = t7;
            }
            e = en;
        }
        float dn = P.dis[n];
        float sn = dn * dn;
        uint4 un = xwq[(size_t)n * 4];
        float4 vn0 = bf4_to_f4(make_uint2(un.x, un.y));
        float4 vn1 = bf4_to_f4(make_uint2(un.z, un.w));
        float4 bb0 = *(const float4*)&P.b[c * 8];
        float4 bb1 = *(const float4*)&P.b[c * 8 + 4];
        sum0.x = fmaf(sn, vn0.x, sum0.x) + bb0.x;
        sum0.y = fmaf(sn, vn0.y, sum0.y) + bb0.y;
        sum0.z = fmaf(sn, vn0.z, sum0.z) + bb0.z;
        sum0.w = fmaf(sn, vn0.w, sum0.w) + bb0.w;
        sum1.x = fmaf(sn, vn1.x, sum1.x) + bb1.x;
        sum1.y = fmaf(sn, vn1.y, sum1.y) + bb1.y;
        sum1.z = fmaf(sn, vn1.z, sum1.z) + bb1.z;
        sum1.w = fmaf(sn, vn1.w, sum1.w) + bb1.w;
        float4 w40 = *(const float4*)&P.wt[c * 8];
        float4 w41 = *(const float4*)&P.wt[c * 8 + 4];
        float t = A.t;
        float4 kv0, kv1;
        kv0.x = fmaxf(sum0.x, 0.f) / (1.f + __expf(-t * w40.x));
        kv0.y = fmaxf(sum0.y, 0.f) / (1.f + __expf(-t * w40.y));
        kv0.z = fmaxf(sum0.z, 0.f) / (1.f + __expf(-t * w40.z));
        kv0.w = fmaxf(sum0.w, 0.f) / (1.f + __expf(-t * w40.w));
        kv1.x = fmaxf(sum1.x, 0.f) / (1.f + __expf(-t * w41.x));
        kv1.y = fmaxf(sum1.y, 0.f) / (1.f + __expf(-t * w41.y));
        kv1.z = fmaxf(sum1.z, 0.f) / (1.f + __expf(-t * w41.z));
        kv1.w = fmaxf(sum1.w, 0.f) / (1.f + __expf(-t * w41.w));

        size_t o = (size_t)n * DIM + c * 8;
        size_t oa = (size_t)n * 4 + c;
        float4 xc0 = nt_load_f4(&P.x_cur[o]);
        float4 xc1 = nt_load_f4(&P.x_cur[o + 4]);
        if (A.mode == 1) {
            nt_store_u4(&P.acc[oa],
                        make_uint4(pack_bf2(kv0.x, kv0.y), pack_bf2(kv0.z, kv0.w),
                                   pack_bf2(kv1.x, kv1.y), pack_bf2(kv1.z, kv1.w)));
            float sc = A.stage_coef;
            r40.x = fmaf(sc, kv0.x, xc0.x); r40.y = fmaf(sc, kv0.y, xc0.y);
            r40.z = fmaf(sc, kv0.z, xc0.z); r40.w = fmaf(sc, kv0.w, xc0.w);
            r41.x = fmaf(sc, kv1.x, xc1.x); r41.y = fmaf(sc, kv1.y, xc1.y);
            r41.z = fmaf(sc, kv1.z, xc1.z); r41.w = fmaf(sc, kv1.w, xc1.w);
        } else {
            uint4 apu = nt_load_u4(&P.acc[oa]);
            float4 ap0 = bf4_to_f4(make_uint2(apu.x, apu.y));
            float4 ap1 = bf4_to_f4(make_uint2(apu.z, apu.w));
            if (A.mode <= 3) {
                float ac = A.acc_coef, sc = A.stage_coef;
                float4 a0, a1;
                a0.x = fmaf(ac, kv0.x, ap0.x); a0.y = fmaf(ac, kv0.y, ap0.y);
                a0.z = fmaf(ac, kv0.z, ap0.z); a0.w = fmaf(ac, kv0.w, ap0.w);
                a1.x = fmaf(ac, kv1.x, ap1.x); a1.y = fmaf(ac, kv1.y, ap1.y);
                a1.z = fmaf(ac, kv1.z, ap1.z); a1.w = fmaf(ac, kv1.w, ap1.w);
                nt_store_u4(&P.acc[oa],
                            make_uint4(pack_bf2(a0.x, a0.y), pack_bf2(a0.z, a0.w),
                                       pack_bf2(a1.x, a1.y), pack_bf2(a1.z, a1.w)));
                r40.x = fmaf(sc, kv0.x, xc0.x); r40.y = fmaf(sc, kv0.y, xc0.y);
                r40.z = fmaf(sc, kv0.z, xc0.z); r40.w = fmaf(sc, kv0.w, xc0.w);
                r41.x = fmaf(sc, kv1.x, xc1.x); r41.y = fmaf(sc, kv1.y, xc1.y);
                r41.z = fmaf(sc, kv1.z, xc1.z); r41.w = fmaf(sc, kv1.w, xc1.w);
            } else {
                float4 a0, a1;
                a0.x = ap0.x + kv0.x; a0.y = ap0.y + kv0.y;
                a0.z = ap0.z + kv0.z; a0.w = ap0.w + kv0.w;
                a1.x = ap1.x + kv1.x; a1.y = ap1.y + kv1.y;
                a1.z = ap1.z + kv1.z; a1.w = ap1.w + kv1.w;
                r40.x = fmaf(HS / 6.f, a0.x, xc0.x); r40.y = fmaf(HS / 6.f, a0.y, xc0.y);
                r40.z = fmaf(HS / 6.f, a0.z, xc0.z); r40.w = fmaf(HS / 6.f, a0.w, xc0.w);
                r41.x = fmaf(HS / 6.f, a1.x, xc1.x); r41.y = fmaf(HS / 6.f, a1.y, xc1.y);
                r41.z = fmaf(HS / 6.f, a1.z, xc1.z); r41.w = fmaf(HS / 6.f, a1.w, xc1.w);
                if (A.mode == 4) {
                    nt_store_f4(&P.x_cur[o], r40);
                    nt_store_f4(&P.x_cur[o + 4], r41);
                } else {
                    int no = P.oldid[n];
                    size_t oo = (size_t)no * DIM + c * 8;
                    nt_store_f4(&P.zout[oo], r40);
                    nt_store_f4(&P.zout[oo + 4], r41);
                }
            }
        }
    }

    if (A.mode == 5) return;  // uniform; no thread reaches the barrier

    // epilogue matmul: xw_out[n] = r4-row @ W, stored bf16 (NT)
    *(float4*)&sR[nl * 36 + c * 8] = r40;
    *(float4*)&sR[nl * 36 + c * 8 + 4] = r41;
    __syncthreads();
    if (active) {
        float4 y0 = make_float4(0.f, 0.f, 0.f, 0.f);
        float4 y1 = make_float4(0.f, 0.f, 0.f, 0.f);
        const float* row = &sR[nl * 36];
#pragma unroll
        for (int i = 0; i < DIM; i++) {
            float sv = row[i];
            float4 wA = *(const float4*)&sW[i * DIM + c * 8];
            float4 wB = *(const float4*)&sW[i * DIM + c * 8 + 4];
            y0.x = fmaf(sv, wA.x, y0.x); y0.y = fmaf(sv, wA.y, y0.y);
            y0.z = fmaf(sv, wA.z, y0.z); y0.w = fmaf(sv, wA.w, y0.w);
            y1.x = fmaf(sv, wB.x, y1.x); y1.y = fmaf(sv, wB.y, y1.y);
            y1.z = fmaf(sv, wB.z, y1.z); y1.w = fmaf(sv, wB.w, y1.w);
        }
        nt_store_u4(&P.xw_out[(size_t)n * 4 + c],
                    make_uint4(pack_bf2(y0.x, y0.y), pack_bf2(y0.z, y0.w),
                               pack_bf2(y1.x, y1.y), pack_bf2(y1.z, y1.w)));
    }
}

// ---------------- host ----------------

extern "C" void kernel_launch(void* const* d_in, const int* in_sizes, int n_in,
                              void* d_out, int out_size, void* d_ws, size_t ws_size,
                              hipStream_t stream) {
    const float* x   = (const float*)d_in[0];
    const int* epos  = (const int*)d_in[1];
    const int* eneg  = (const int*)d_in[2];
    const float* Wp  = (const float*)d_in[3];
    const float* bp  = (const float*)d_in[4];
    const float* wtp = (const float*)d_in[5];
    const float* Wn  = (const float*)d_in[6];
    const float* bn  = (const float*)d_in[7];
    const float* wtn = (const float*)d_in[8];
    float* out = (float*)d_out;

    char* ws = (char*)d_ws;
    size_t off = 0;
    auto alloc = [&](size_t bytes) -> void* {
        void* p = ws + off;
        off += (bytes + 255) & ~(size_t)255;
        return p;
    };

    struct Sign {
        int *row_ptr, *cnt, *fill, *H, *Hc, *base, *partials;
        int *newid, *oldid, *degn;
        float *disn, *diso;
        unsigned* cw;
        float* x_cur;
        uint4* acc;
        uint4* xwbuf[2];
        const int *src, *dst;
        const float *W, *b, *wt;
        float* zout;
    } S[2];

    const size_t CWCAP = (size_t)NE + 8u * NN;  // padded capacity

    for (int s = 0; s < 2; s++) {
        S[s].row_ptr  = (int*)alloc((NN + 1) * sizeof(int));
        int* zblock   = (int*)alloc(((size_t)2 * NN + 256) * sizeof(int));
        S[s].cnt = zblock;            // NN
        S[s].fill = zblock + NN;      // NN
        S[s].H = zblock + 2 * NN;     // 128
        S[s].Hc = zblock + 2 * NN + 128;  // 128
        S[s].base     = (int*)alloc(128 * sizeof(int));
        S[s].partials = (int*)alloc(256);
        S[s].newid    = (int*)alloc(NN * sizeof(int));
        S[s].oldid    = (int*)alloc(NN * sizeof(int));
        S[s].degn     = (int*)alloc(NN * sizeof(int));
        S[s].disn     = (float*)alloc(NN * sizeof(float));
        S[s].diso     = (float*)alloc(NN * sizeof(float));
        S[s].cw       = (unsigned*)alloc(CWCAP * sizeof(unsigned));
        S[s].x_cur    = (float*)alloc((size_t)NN * DIM * sizeof(float));
        S[s].acc      = (uint4*)alloc((size_t)NN * DIM * 2);
        S[s].xwbuf[0] = (uint4*)alloc((size_t)NN * DIM * 2);
        S[s].xwbuf[1] = (uint4*)alloc((size_t)NN * DIM * 2);
    }
    S[0].src = epos; S[0].dst = epos + NE; S[0].W = Wp; S[0].b = bp; S[0].wt = wtp;
    S[0].zout = out;
    S[1].src = eneg; S[1].dst = eneg + NE; S[1].W = Wn; S[1].b = bn; S[1].wt = wtn;
    S[1].zout = out + (size_t)NN * DIM;

    const int nbScan = cdiv(NN, 1024);

    // ---- setup: degree sort + padded CSR (new-id space) for both signs ----
    for (int s = 0; s < 2; s++) {
        k_zero_ints<<<cdiv(2 * NN + 256, 256), 256, 0, stream>>>(S[s].cnt, 2 * NN + 256);
        k_hist<<<cdiv(NE, 256), 256, 0, stream>>>(S[s].dst, S[s].cnt);
        k_deghist<<<cdiv(NN, 256), 256, 0, stream>>>(S[s].cnt, S[s].H);
        k_degbase<<<1, 1, 0, stream>>>(S[s].H, S[s].base);
        k_newid<<<cdiv(NN, 256), 256, 0, stream>>>(S[s].cnt, S[s].base, S[s].Hc,
                                                   S[s].newid, S[s].oldid, S[s].degn,
                                                   S[s].disn, S[s].diso);
        k_scanA<<<nbScan, 1024, 0, stream>>>(S[s].degn, S[s].row_ptr, S[s].partials);
        k_scanB<<<1, 1, 0, stream>>>(S[s].partials, nbScan);
        k_scanC<<<cdiv(NN, 256), 256, 0, stream>>>(S[s].row_ptr, S[s].partials);
        k_fill<<<cdiv(NE, 256), 256, 0, stream>>>(S[s].src, S[s].dst, S[s].row_ptr,
                                                  S[s].diso, S[s].newid, S[s].fill,
                                                  S[s].cw);
        k_pad<<<cdiv(NN, 256), 256, 0, stream>>>(S[s].row_ptr, S[s].degn, S[s].cw);
    }

    // initial xw = bf16(x @ W) permuted, x_cur = x permuted
    for (int s = 0; s < 2; s++)
        k_matmul<<<cdiv(NN, 32), 256, 0, stream>>>(x, S[s].W, S[s].newid,
                                                   (uint2*)S[s].xwbuf[0], S[s].x_cur);

    // ---- RK4 main loop: 4 fused stages per step, both signs per dispatch ----
    for (int st = 0; st < 10; st++) {
        float tb = HS * (float)st;
        struct Ph { float t, ac, sc; int mode, in, out; } ph[4] = {
            { tb,             1.f, HS * 0.5f, 1,              0, 1 },
            { tb + HS * 0.5f, 2.f, HS * 0.5f, 2,              1, 0 },
            { tb + HS * 0.5f, 2.f, HS,        3,              0, 1 },
            { tb + HS,        1.f, 0.f,       st == 9 ? 5 : 4, 1, 0 },
        };
        for (int p = 0; p < 4; p++) {
            StageArgs A;
            for (int s = 0; s < 2; s++) {
                A.s[s].row_ptr = S[s].row_ptr;
                A.s[s].cw      = S[s].cw;
                A.s[s].dis     = S[s].disn;
                A.s[s].xw_in   = S[s].xwbuf[ph[p].in];
                A.s[s].xw_out  = S[s].xwbuf[ph[p].out];
                A.s[s].acc     = S[s].acc;
                A.s[s].x_cur   = S[s].x_cur;
                A.s[s].W       = S[s].W;
                A.s[s].b       = S[s].b;
                A.s[s].wt      = S[s].wt;
                A.s[s].oldid   = S[s].oldid;
                A.s[s].zout    = S[s].zout;
            }
            A.t = ph[p].t; A.acc_coef = ph[p].ac; A.stage_coef = ph[p].sc;
            A.mode = ph[p].mode;
            k_stage<<<2 * NBPS, 256, 0, stream>>>(A);
        }
    }
}

// Round 9
// 1707.704 us; speedup vs baseline: 1.1895x; 1.1895x over previous
//
#include <hip/hip_runtime.h>

#define NN 50000
#define NE 1600000
#define DIM 32
#define HS 0.1f
#define NBPS 782       // cdiv(NN, 64) blocks per sign
#define NB 196         // cdiv(NN, 256) histogram blocks
#define NBIN 128

static inline int cdiv(int a, int b) { return (a + b - 1) / b; }

typedef float vf4 __attribute__((ext_vector_type(4)));
typedef unsigned vu4 __attribute__((ext_vector_type(4)));

__device__ __forceinline__ float4 nt_load_f4(const float* p) {
    vf4 v = __builtin_nontemporal_load((const vf4*)p);
    return make_float4(v.x, v.y, v.z, v.w);
}
__device__ __forceinline__ void nt_store_f4(float* p, float4 v) {
    vf4 t = {v.x, v.y, v.z, v.w};
    __builtin_nontemporal_store(t, (vf4*)p);
}
__device__ __forceinline__ uint4 nt_load_u4(const uint4* p) {
    vu4 v = __builtin_nontemporal_load((const vu4*)p);
    return make_uint4(v.x, v.y, v.z, v.w);
}
__device__ __forceinline__ void nt_store_u4(uint4* p, uint4 v) {
    vu4 t = {v.x, v.y, v.z, v.w};
    __builtin_nontemporal_store(t, (vu4*)p);
}

// bf16x4 (uint2) -> float4
__device__ __forceinline__ float4 bf4_to_f4(uint2 u) {
    float4 v;
    v.x = __uint_as_float(u.x << 16);
    v.y = __uint_as_float(u.x & 0xffff0000u);
    v.z = __uint_as_float(u.y << 16);
    v.w = __uint_as_float(u.y & 0xffff0000u);
    return v;
}
__device__ __forceinline__ unsigned pack_bf2(float a, float b) {
    unsigned ua = __float_as_uint(a);
    ua = (ua + 0x7fffu + ((ua >> 16) & 1u)) >> 16;
    unsigned ub = __float_as_uint(b);
    ub = (ub + 0x7fffu + ((ub >> 16) & 1u)) & 0xffff0000u;
    return ua | ub;
}

// ---------------- setup kernels ----------------

__global__ void k_zero_ints(int* __restrict__ p, int n) {
    int i = blockIdx.x * blockDim.x + threadIdx.x;
    if (i < n) p[i] = 0;
}

__global__ void k_hist(const int* __restrict__ dst, int* __restrict__ cnt) {
    int i = blockIdx.x * blockDim.x + threadIdx.x;
    if (i < NE) atomicAdd(&cnt[dst[i]], 1);
}

// per-block LDS degree histogram -> blockbins[bin*NB + blk], global H via few atomics
__global__ __launch_bounds__(256) void k_bcnt(const int* __restrict__ cnt,
                                              int* __restrict__ blockbins,
                                              int* __restrict__ H) {
    __shared__ int lh[NBIN];
    int t = threadIdx.x;
    if (t < NBIN) lh[t] = 0;
    __syncthreads();
    int n = blockIdx.x * 256 + t;
    if (n < NN) atomicAdd(&lh[min(cnt[n], NBIN - 1)], 1);
    __syncthreads();
    if (t < NBIN) {
        int v = lh[t];
        blockbins[t * NB + blockIdx.x] = v;
        if (v) atomicAdd(&H[t], v);
    }
}

// descending-degree bases: base[d] = #nodes with bin > d
__global__ void k_degbase(const int* __restrict__ H, int* __restrict__ base) {
    if (threadIdx.x == 0 && blockIdx.x == 0) {
        int run = 0;
        for (int d = NBIN - 1; d >= 0; --d) { base[d] = run; run += H[d]; }
    }
}

// per-bin exclusive scan over blocks (128 threads, each owns one bin)
__global__ __launch_bounds__(128) void k_binscan(int* __restrict__ blockbins) {
    int bin = threadIdx.x;
    int run = 0;
    for (int b = 0; b < NB; ++b) {
        int v = blockbins[bin * NB + b];
        blockbins[bin * NB + b] = run;
        run += v;
    }
}

// assign new ids: nid = base[bin] + blockoff[bin][blk] + local rank (LDS atomics only)
__global__ __launch_bounds__(256) void k_newid2(const int* __restrict__ cnt,
                                                const int* __restrict__ base,
                                                const int* __restrict__ blockbins,
                                                int* __restrict__ newid,
                                                int* __restrict__ oldid,
                                                int* __restrict__ degn,
                                                float* __restrict__ disn,
                                                float* __restrict__ diso) {
    __shared__ int lcnt[NBIN];
    int t = threadIdx.x;
    if (t < NBIN) lcnt[t] = 0;
    __syncthreads();
    int n = blockIdx.x * 256 + t;
    if (n < NN) {
        int d = cnt[n];
        int db = min(d, NBIN - 1);
        int lrank = atomicAdd(&lcnt[db], 1);
        int nid = base[db] + blockbins[db * NB + blockIdx.x] + lrank;
        newid[n] = nid;
        oldid[nid] = n;
        degn[nid] = d;
        float r = rsqrtf((float)d + 1.0f);  // +1 self-loop
        disn[nid] = r;
        diso[n] = r;
    }
}

// prefix over PADDED degree (rounded up to 8), new-id space -> row_ptr
__global__ __launch_bounds__(1024) void k_scanA(const int* __restrict__ degn,
                                                int* __restrict__ row_ptr,
                                                int* __restrict__ partials) {
    __shared__ int s[1024];
    int t = threadIdx.x;
    int g = blockIdx.x * 1024 + t;
    int v = (g < NN) ? ((degn[g] + 7) & ~7) : 0;
    s[t] = v;
    __syncthreads();
    for (int off = 1; off < 1024; off <<= 1) {
        int add = (t >= off) ? s[t - off] : 0;
        __syncthreads();
        s[t] += add;
        __syncthreads();
    }
    if (g < NN) row_ptr[g + 1] = s[t];
    if (t == 1023) partials[blockIdx.x] = s[t];
}

__global__ void k_scanB(int* __restrict__ partials, int nb) {
    if (threadIdx.x == 0 && blockIdx.x == 0) {
        int run = 0;
        for (int i = 0; i < nb; i++) { int v = partials[i]; partials[i] = run; run += v; }
    }
}

__global__ void k_scanC(int* __restrict__ row_ptr, const int* __restrict__ partials) {
    int g = blockIdx.x * blockDim.x + threadIdx.x;
    if (g < NN) row_ptr[g + 1] += partials[g >> 10];
    if (g == 0) row_ptr[0] = 0;
}

// scatter edges; rec = (newid[src] << 15) | fix15(dis[s]*dis[d]); CSR in new-id space
__global__ void k_fill(const int* __restrict__ src, const int* __restrict__ dst,
                       const int* __restrict__ row_ptr, const float* __restrict__ diso,
                       const int* __restrict__ newid,
                       int* __restrict__ fill, unsigned* __restrict__ cw) {
    int i = blockIdx.x * blockDim.x + threadIdx.x;
    if (i < NE) {
        int s = src[i], d = dst[i];
        int nd = newid[d];
        int slot = row_ptr[nd] + atomicAdd(&fill[nd], 1);
        float w = diso[s] * diso[d];   // in (0, 1]
        cw[slot] = ((unsigned)newid[s] << 15) | (unsigned)(w * 32767.f + 0.5f);
    }
}

// zero the pad slots (rec=0 -> src 0, weight 0)
__global__ void k_pad(const int* __restrict__ row_ptr, const int* __restrict__ degn,
                      unsigned* __restrict__ cw) {
    int n = blockIdx.x * blockDim.x + threadIdx.x;
    if (n < NN) {
        int e = row_ptr[n] + degn[n], e1 = row_ptr[n + 1];
        for (; e < e1; ++e) cw[e] = 0u;
    }
}

// ---------------- initial matmul (x @ W -> xw bf16 permuted, x -> x_cur permuted) ----

__global__ __launch_bounds__(256) void k_matmul(const float* __restrict__ src,
                                                const float* __restrict__ W,
                                                const int* __restrict__ newid,
                                                uint2* __restrict__ xw,
                                                float* __restrict__ copy_out) {
    __shared__ float sW[DIM * DIM];
    __shared__ float sX[32 * 33];
    int t = threadIdx.x;
#pragma unroll
    for (int k = 0; k < 4; k++) { int i = k * 256 + t; sW[i] = W[i]; }
    size_t base = (size_t)blockIdx.x * 32 * DIM;
#pragma unroll
    for (int k = 0; k < 4; k++) {
        int i = k * 256 + t;
        size_t g = base + i;
        float v = 0.f;
        if (g < (size_t)NN * DIM) {
            v = src[g];
            int ro = (int)(g >> 5), col = (int)(g & 31);
            copy_out[(size_t)newid[ro] * DIM + col] = v;
        }
        sX[(i >> 5) * 33 + (i & 31)] = v;
    }
    __syncthreads();
    int r = t >> 3, oct = t & 7;
    int row = blockIdx.x * 32 + r;
    if (row >= NN) return;
    float a0 = 0.f, a1 = 0.f, a2 = 0.f, a3 = 0.f;
    const float* xr = &sX[r * 33];
#pragma unroll
    for (int i = 0; i < DIM; i++) {
        float xv = xr[i];
        const float* wr = &sW[i * DIM + oct * 4];
        a0 = fmaf(xv, wr[0], a0);
        a1 = fmaf(xv, wr[1], a1);
        a2 = fmaf(xv, wr[2], a2);
        a3 = fmaf(xv, wr[3], a3);
    }
    xw[(size_t)newid[row] * 8 + oct] = make_uint2(pack_bf2(a0, a1), pack_bf2(a2, a3));
}

// ---------------- fused stage kernel ----------------
// Degree-sorted (new-id) node space: lane-groups in a wave have near-equal
// degree. Streams (x_cur, acc, stores) non-temporal; cw + gathers cached.
// acc is bf16.

struct SignP {
    const int* row_ptr; const unsigned* cw; const float* dis;
    const uint4* xw_in; uint4* xw_out;
    uint4* acc; float* x_cur;
    const float* W; const float* b; const float* wt;
    const int* oldid;
    float* zout;
};
struct StageArgs { SignP s[2]; float t, acc_coef, stage_coef; int mode; };

#define EDGE_FMA(r, u)                                              \
    {                                                               \
        float wE = (float)((r) & 32767u) * (1.f / 32767.f);         \
        float4 vA = bf4_to_f4(make_uint2((u).x, (u).y));            \
        float4 vB = bf4_to_f4(make_uint2((u).z, (u).w));            \
        sum0.x = fmaf(wE, vA.x, sum0.x);                            \
        sum0.y = fmaf(wE, vA.y, sum0.y);                            \
        sum0.z = fmaf(wE, vA.z, sum0.z);                            \
        sum0.w = fmaf(wE, vA.w, sum0.w);                            \
        sum1.x = fmaf(wE, vB.x, sum1.x);                            \
        sum1.y = fmaf(wE, vB.y, sum1.y);                            \
        sum1.z = fmaf(wE, vB.z, sum1.z);                            \
        sum1.w = fmaf(wE, vB.w, sum1.w);                            \
    }

__global__ __launch_bounds__(256) void k_stage(StageArgs A) {
    int sg = blockIdx.x & 1;       // with 8-XCD round-robin: sign per XCD parity
    int blk = blockIdx.x >> 1;
    SignP P = A.s[sg];

    __shared__ float sW[DIM * DIM];   // 4 KB
    __shared__ float sR[64 * 36];     // 9 KB; stride 36 floats
    int tid = threadIdx.x;
    if (A.mode != 5) {
#pragma unroll
        for (int k = 0; k < 4; k++) { int i = k * 256 + tid; sW[i] = P.W[i]; }
    }

    int c = tid & 3;              // column octet: cols c*8 .. c*8+7
    int nl = tid >> 2;            // local node 0..63
    int n = blk * 64 + nl;
    bool active = n < NN;
    float4 r40 = make_float4(0.f, 0.f, 0.f, 0.f);
    float4 r41 = make_float4(0.f, 0.f, 0.f, 0.f);

    if (active) {
        int e = P.row_ptr[n], e1 = P.row_ptr[n + 1];   // (e1-e) % 8 == 0
        const uint4* xwq = P.xw_in + c;   // row stride = 4 uint4 (64 B)
        float4 sum0 = make_float4(0.f, 0.f, 0.f, 0.f);
        float4 sum1 = make_float4(0.f, 0.f, 0.f, 0.f);
        unsigned r0, r1, r2, r3, r4, r5, r6, r7;
        if (e < e1) {
            r0 = P.cw[e];     r1 = P.cw[e + 1]; r2 = P.cw[e + 2]; r3 = P.cw[e + 3];
            r4 = P.cw[e + 4]; r5 = P.cw[e + 5]; r6 = P.cw[e + 6]; r7 = P.cw[e + 7];
        }
        while (e < e1) {
            uint4 u0 = xwq[(size_t)(r0 >> 15) * 4];
            uint4 u1 = xwq[(size_t)(r1 >> 15) * 4];
            uint4 u2 = xwq[(size_t)(r2 >> 15) * 4];
            uint4 u3 = xwq[(size_t)(r3 >> 15) * 4];
            uint4 u4 = xwq[(size_t)(r4 >> 15) * 4];
            uint4 u5 = xwq[(size_t)(r5 >> 15) * 4];
            uint4 u6 = xwq[(size_t)(r6 >> 15) * 4];
            uint4 u7 = xwq[(size_t)(r7 >> 15) * 4];
            int en = e + 8;
            unsigned t0, t1, t2, t3, t4, t5, t6, t7;
            if (en < e1) {
                t0 = P.cw[en];     t1 = P.cw[en + 1]; t2 = P.cw[en + 2]; t3 = P.cw[en + 3];
                t4 = P.cw[en + 4]; t5 = P.cw[en + 5]; t6 = P.cw[en + 6]; t7 = P.cw[en + 7];
            }
            EDGE_FMA(r0, u0) EDGE_FMA(r1, u1) EDGE_FMA(r2, u2) EDGE_FMA(r3, u3)
            EDGE_FMA(r4, u4) EDGE_FMA(r5, u5) EDGE_FMA(r6, u6) EDGE_FMA(r7, u7)
            if (en < e1) {
                r0 = t0; r1 = t1; r2 = t2; r3 = t3;
                r4 = t4; r5 = t5; r6 = t6; r7 = t7;
            }
            e = en;
        }
        float dn = P.dis[n];
        float sn = dn * dn;
        uint4 un = xwq[(size_t)n * 4];
        float4 vn0 = bf4_to_f4(make_uint2(un.x, un.y));
        float4 vn1 = bf4_to_f4(make_uint2(un.z, un.w));
        float4 bb0 = *(const float4*)&P.b[c * 8];
        float4 bb1 = *(const float4*)&P.b[c * 8 + 4];
        sum0.x = fmaf(sn, vn0.x, sum0.x) + bb0.x;
        sum0.y = fmaf(sn, vn0.y, sum0.y) + bb0.y;
        sum0.z = fmaf(sn, vn0.z, sum0.z) + bb0.z;
        sum0.w = fmaf(sn, vn0.w, sum0.w) + bb0.w;
        sum1.x = fmaf(sn, vn1.x, sum1.x) + bb1.x;
        sum1.y = fmaf(sn, vn1.y, sum1.y) + bb1.y;
        sum1.z = fmaf(sn, vn1.z, sum1.z) + bb1.z;
        sum1.w = fmaf(sn, vn1.w, sum1.w) + bb1.w;
        float4 w40 = *(const float4*)&P.wt[c * 8];
        float4 w41 = *(const float4*)&P.wt[c * 8 + 4];
        float t = A.t;
        float4 kv0, kv1;
        kv0.x = fmaxf(sum0.x, 0.f) / (1.f + __expf(-t * w40.x));
        kv0.y = fmaxf(sum0.y, 0.f) / (1.f + __expf(-t * w40.y));
        kv0.z = fmaxf(sum0.z, 0.f) / (1.f + __expf(-t * w40.z));
        kv0.w = fmaxf(sum0.w, 0.f) / (1.f + __expf(-t * w40.w));
        kv1.x = fmaxf(sum1.x, 0.f) / (1.f + __expf(-t * w41.x));
        kv1.y = fmaxf(sum1.y, 0.f) / (1.f + __expf(-t * w41.y));
        kv1.z = fmaxf(sum1.z, 0.f) / (1.f + __expf(-t * w41.z));
        kv1.w = fmaxf(sum1.w, 0.f) / (1.f + __expf(-t * w41.w));

        size_t o = (size_t)n * DIM + c * 8;
        size_t oa = (size_t)n * 4 + c;
        float4 xc0 = nt_load_f4(&P.x_cur[o]);
        float4 xc1 = nt_load_f4(&P.x_cur[o + 4]);
        if (A.mode == 1) {
            nt_store_u4(&P.acc[oa],
                        make_uint4(pack_bf2(kv0.x, kv0.y), pack_bf2(kv0.z, kv0.w),
                                   pack_bf2(kv1.x, kv1.y), pack_bf2(kv1.z, kv1.w)));
            float sc = A.stage_coef;
            r40.x = fmaf(sc, kv0.x, xc0.x); r40.y = fmaf(sc, kv0.y, xc0.y);
            r40.z = fmaf(sc, kv0.z, xc0.z); r40.w = fmaf(sc, kv0.w, xc0.w);
            r41.x = fmaf(sc, kv1.x, xc1.x); r41.y = fmaf(sc, kv1.y, xc1.y);
            r41.z = fmaf(sc, kv1.z, xc1.z); r41.w = fmaf(sc, kv1.w, xc1.w);
        } else {
            uint4 apu = nt_load_u4(&P.acc[oa]);
            float4 ap0 = bf4_to_f4(make_uint2(apu.x, apu.y));
            float4 ap1 = bf4_to_f4(make_uint2(apu.z, apu.w));
            if (A.mode <= 3) {
                float ac = A.acc_coef, sc = A.stage_coef;
                float4 a0, a1;
                a0.x = fmaf(ac, kv0.x, ap0.x); a0.y = fmaf(ac, kv0.y, ap0.y);
                a0.z = fmaf(ac, kv0.z, ap0.z); a0.w = fmaf(ac, kv0.w, ap0.w);
                a1.x = fmaf(ac, kv1.x, ap1.x); a1.y = fmaf(ac, kv1.y, ap1.y);
                a1.z = fmaf(ac, kv1.z, ap1.z); a1.w = fmaf(ac, kv1.w, ap1.w);
                nt_store_u4(&P.acc[oa],
                            make_uint4(pack_bf2(a0.x, a0.y), pack_bf2(a0.z, a0.w),
                                       pack_bf2(a1.x, a1.y), pack_bf2(a1.z, a1.w)));
                r40.x = fmaf(sc, kv0.x, xc0.x); r40.y = fmaf(sc, kv0.y, xc0.y);
                r40.z = fmaf(sc, kv0.z, xc0.z); r40.w = fmaf(sc, kv0.w, xc0.w);
                r41.x = fmaf(sc, kv1.x, xc1.x); r41.y = fmaf(sc, kv1.y, xc1.y);
                r41.z = fmaf(sc, kv1.z, xc1.z); r41.w = fmaf(sc, kv1.w, xc1.w);
            } else {
                float4 a0, a1;
                a0.x = ap0.x + kv0.x; a0.y = ap0.y + kv0.y;
                a0.z = ap0.z + kv0.z; a0.w = ap0.w + kv0.w;
                a1.x = ap1.x + kv1.x; a1.y = ap1.y + kv1.y;
                a1.z = ap1.z + kv1.z; a1.w = ap1.w + kv1.w;
                r40.x = fmaf(HS / 6.f, a0.x, xc0.x); r40.y = fmaf(HS / 6.f, a0.y, xc0.y);
                r40.z = fmaf(HS / 6.f, a0.z, xc0.z); r40.w = fmaf(HS / 6.f, a0.w, xc0.w);
                r41.x = fmaf(HS / 6.f, a1.x, xc1.x); r41.y = fmaf(HS / 6.f, a1.y, xc1.y);
                r41.z = fmaf(HS / 6.f, a1.z, xc1.z); r41.w = fmaf(HS / 6.f, a1.w, xc1.w);
                if (A.mode == 4) {
                    nt_store_f4(&P.x_cur[o], r40);
                    nt_store_f4(&P.x_cur[o + 4], r41);
                } else {
                    int no = P.oldid[n];
                    size_t oo = (size_t)no * DIM + c * 8;
                    nt_store_f4(&P.zout[oo], r40);
                    nt_store_f4(&P.zout[oo + 4], r41);
                }
            }
        }
    }

    if (A.mode == 5) return;  // uniform; no thread reaches the barrier

    // epilogue matmul: xw_out[n] = r4-row @ W, stored bf16 (NT)
    *(float4*)&sR[nl * 36 + c * 8] = r40;
    *(float4*)&sR[nl * 36 + c * 8 + 4] = r41;
    __syncthreads();
    if (active) {
        float4 y0 = make_float4(0.f, 0.f, 0.f, 0.f);
        float4 y1 = make_float4(0.f, 0.f, 0.f, 0.f);
        const float* row = &sR[nl * 36];
#pragma unroll
        for (int i = 0; i < DIM; i++) {
            float sv = row[i];
            float4 wA = *(const float4*)&sW[i * DIM + c * 8];
            float4 wB = *(const float4*)&sW[i * DIM + c * 8 + 4];
            y0.x = fmaf(sv, wA.x, y0.x); y0.y = fmaf(sv, wA.y, y0.y);
            y0.z = fmaf(sv, wA.z, y0.z); y0.w = fmaf(sv, wA.w, y0.w);
            y1.x = fmaf(sv, wB.x, y1.x); y1.y = fmaf(sv, wB.y, y1.y);
            y1.z = fmaf(sv, wB.z, y1.z); y1.w = fmaf(sv, wB.w, y1.w);
        }
        nt_store_u4(&P.xw_out[(size_t)n * 4 + c],
                    make_uint4(pack_bf2(y0.x, y0.y), pack_bf2(y0.z, y0.w),
                               pack_bf2(y1.x, y1.y), pack_bf2(y1.z, y1.w)));
    }
}

// ---------------- host ----------------

extern "C" void kernel_launch(void* const* d_in, const int* in_sizes, int n_in,
                              void* d_out, int out_size, void* d_ws, size_t ws_size,
                              hipStream_t stream) {
    const float* x   = (const float*)d_in[0];
    const int* epos  = (const int*)d_in[1];
    const int* eneg  = (const int*)d_in[2];
    const float* Wp  = (const float*)d_in[3];
    const float* bp  = (const float*)d_in[4];
    const float* wtp = (const float*)d_in[5];
    const float* Wn  = (const float*)d_in[6];
    const float* bn  = (const float*)d_in[7];
    const float* wtn = (const float*)d_in[8];
    float* out = (float*)d_out;

    char* ws = (char*)d_ws;
    size_t off = 0;
    auto alloc = [&](size_t bytes) -> void* {
        void* p = ws + off;
        off += (bytes + 255) & ~(size_t)255;
        return p;
    };

    struct Sign {
        int *row_ptr, *cnt, *fill, *H, *base, *blockbins, *partials;
        int *newid, *oldid, *degn;
        float *disn, *diso;
        unsigned* cw;
        float* x_cur;
        uint4* acc;
        uint4* xwbuf[2];
        const int *src, *dst;
        const float *W, *b, *wt;
        float* zout;
    } S[2];

    const size_t CWCAP = (size_t)NE + 8u * NN;  // padded capacity

    for (int s = 0; s < 2; s++) {
        S[s].row_ptr  = (int*)alloc((NN + 1) * sizeof(int));
        int* zblock   = (int*)alloc(((size_t)2 * NN + NBIN) * sizeof(int));
        S[s].cnt = zblock;            // NN
        S[s].fill = zblock + NN;      // NN
        S[s].H = zblock + 2 * NN;     // NBIN
        S[s].base      = (int*)alloc(NBIN * sizeof(int));
        S[s].blockbins = (int*)alloc((size_t)NBIN * NB * sizeof(int));
        S[s].partials  = (int*)alloc(256);
        S[s].newid     = (int*)alloc(NN * sizeof(int));
        S[s].oldid     = (int*)alloc(NN * sizeof(int));
        S[s].degn      = (int*)alloc(NN * sizeof(int));
        S[s].disn      = (float*)alloc(NN * sizeof(float));
        S[s].diso      = (float*)alloc(NN * sizeof(float));
        S[s].cw        = (unsigned*)alloc(CWCAP * sizeof(unsigned));
        S[s].x_cur     = (float*)alloc((size_t)NN * DIM * sizeof(float));
        S[s].acc       = (uint4*)alloc((size_t)NN * DIM * 2);
        S[s].xwbuf[0]  = (uint4*)alloc((size_t)NN * DIM * 2);
        S[s].xwbuf[1]  = (uint4*)alloc((size_t)NN * DIM * 2);
    }
    S[0].src = epos; S[0].dst = epos + NE; S[0].W = Wp; S[0].b = bp; S[0].wt = wtp;
    S[0].zout = out;
    S[1].src = eneg; S[1].dst = eneg + NE; S[1].W = Wn; S[1].b = bn; S[1].wt = wtn;
    S[1].zout = out + (size_t)NN * DIM;

    const int nbScan = cdiv(NN, 1024);

    // ---- setup: contention-free degree sort + padded CSR (new-id space) ----
    for (int s = 0; s < 2; s++) {
        k_zero_ints<<<cdiv(2 * NN + NBIN, 256), 256, 0, stream>>>(S[s].cnt, 2 * NN + NBIN);
        k_hist<<<cdiv(NE, 256), 256, 0, stream>>>(S[s].dst, S[s].cnt);
        k_bcnt<<<NB, 256, 0, stream>>>(S[s].cnt, S[s].blockbins, S[s].H);
        k_degbase<<<1, 1, 0, stream>>>(S[s].H, S[s].base);
        k_binscan<<<1, 128, 0, stream>>>(S[s].blockbins);
        k_newid2<<<NB, 256, 0, stream>>>(S[s].cnt, S[s].base, S[s].blockbins,
                                         S[s].newid, S[s].oldid, S[s].degn,
                                         S[s].disn, S[s].diso);
        k_scanA<<<nbScan, 1024, 0, stream>>>(S[s].degn, S[s].row_ptr, S[s].partials);
        k_scanB<<<1, 1, 0, stream>>>(S[s].partials, nbScan);
        k_scanC<<<cdiv(NN, 256), 256, 0, stream>>>(S[s].row_ptr, S[s].partials);
        k_fill<<<cdiv(NE, 256), 256, 0, stream>>>(S[s].src, S[s].dst, S[s].row_ptr,
                                                  S[s].diso, S[s].newid, S[s].fill,
                                                  S[s].cw);
        k_pad<<<cdiv(NN, 256), 256, 0, stream>>>(S[s].row_ptr, S[s].degn, S[s].cw);
    }

    // initial xw = bf16(x @ W) permuted, x_cur = x permuted
    for (int s = 0; s < 2; s++)
        k_matmul<<<cdiv(NN, 32), 256, 0, stream>>>(x, S[s].W, S[s].newid,
                                                   (uint2*)S[s].xwbuf[0], S[s].x_cur);

    // ---- RK4 main loop: 4 fused stages per step, both signs per dispatch ----
    for (int st = 0; st < 10; st++) {
        float tb = HS * (float)st;
        struct Ph { float t, ac, sc; int mode, in, out; } ph[4] = {
            { tb,             1.f, HS * 0.5f, 1,              0, 1 },
            { tb + HS * 0.5f, 2.f, HS * 0.5f, 2,              1, 0 },
            { tb + HS * 0.5f, 2.f, HS,        3,              0, 1 },
            { tb + HS,        1.f, 0.f,       st == 9 ? 5 : 4, 1, 0 },
        };
        for (int p = 0; p < 4; p++) {
            StageArgs A;
            for (int s = 0; s < 2; s++) {
                A.s[s].row_ptr = S[s].row_ptr;
                A.s[s].cw      = S[s].cw;
                A.s[s].dis     = S[s].disn;
                A.s[s].xw_in   = S[s].xwbuf[ph[p].in];
                A.s[s].xw_out  = S[s].xwbuf[ph[p].out];
                A.s[s].acc     = S[s].acc;
                A.s[s].x_cur   = S[s].x_cur;
                A.s[s].W       = S[s].W;
                A.s[s].b       = S[s].b;
                A.s[s].wt      = S[s].wt;
                A.s[s].oldid   = S[s].oldid;
                A.s[s].zout    = S[s].zout;
            }
            A.t = ph[p].t; A.acc_coef = ph[p].ac; A.stage_coef = ph[p].sc;
            A.mode = ph[p].mode;
            k_stage<<<2 * NBPS, 256, 0, stream>>>(A);
        }
    }
}